// Round 5
// baseline (216.648 us; speedup 1.0000x reference)
//
#include <hip/hip_runtime.h>
#include <math.h>

// B=4, C=256, H=W=64, G=4, Cg=64, P=9. x [B,HW,C] is NHWC already.
// Convs via implicit-GEMM MFMA (bf16 2-term split: hi*hi + hi*lo + lo*hi).
// Chunked SPLIT-ARRAY layout: activations [ch][b][SLAB px][32] hi/lo arrays.
// R11: XCD swizzle (kept). R13: MT=4, tap-inner (72->58us).
// R12/R14 lesson: duration invariant (~58us) across occupancy/VGPR/pipeline
// changes -> vector-path delivery ~20B/cyc/CU is the wall (L1 thrash: 8 waves
// x private 16KB/iter re-reads, zero cross-wave sharing).
// R15: canonical LDS-staged core. Per block (4 waves = 4 output rows):
//   per ic-chunk: stage 6 input rows (66px, hi+lo) ONCE (vs 9-tap x 4-wave
//   re-reads); per tap: stage B tile ONCE (vs 4 waves x 8KB). MFMA operands
//   now come from LDS (ds_read_b128, padded stride 40 ushorts = 80B: 16B
//   aligned, ~2-way banks = free). Vector path carries staging only (~5x
//   less). Reg-staged ds_write (rule #21: padded layout can't global_load_lds).
//   LDS 73.6/76.2KB -> 2 blocks/CU.

#define SLAB 4369           // padded px per (ch,b) slab (4356 used + 13 pad)
#define AGAP 1056           // ushorts between arrays (kept from R13)
#define APXS 40             // LDS padded px/oc stride in ushorts (80B)
#define AROW (66*APXS)      // 2640 ushorts per LDS A row
#define AHALF (6*AROW)      // 15840 ushorts per A half (6 rows)

typedef __attribute__((ext_vector_type(8))) short short8;
typedef __attribute__((ext_vector_type(4))) float floatx4;

__device__ __forceinline__ unsigned short f2bf(float f) {
    unsigned u = __float_as_uint(f);
    u = (u + 0x7FFFu + ((u >> 16) & 1u)) >> 16;
    return (unsigned short)u;
}
__device__ __forceinline__ float bf2f(unsigned short h) {
    return __uint_as_float(((unsigned)h) << 16);
}
__device__ __forceinline__ void split2(float v, unsigned short* hi, unsigned short* lo) {
    unsigned short h = f2bf(v);
    *hi = h;
    *lo = f2bf(v - bf2f(h));
}
__device__ __forceinline__ float gelu_exact(float v) {
    return 0.5f * v * (1.0f + erff(v * 0.70710678118654752f));
}

// ---------------- LDS-staged MFMA implicit-GEMM conv core ----------------
// Global activations: [ch][b][SLAB px][32] ushort (hi/lo). px = y*66+x, padded.
// Global weights: [ch][tap][OCPAD][32] ushort (hi/lo).
// Block = 4 waves; wave w owns output row y0+w (64 px) x OCPAD oc.
// LDS: A [2 halves][6 rows][66 px][APXS], B [2 halves][OCPAD][APXS].
// A frag: m=l16 -> pixel, k=quad*8+j -> ic. B frag: n=l16 -> oc.
// C/D: col(oc)=lane&15, row(pixel)=quad*4+reg.
// ACT: 0 none, 1 gelu(exact), 2 sigmoid.
// OUTMODE: 1 split-bf16 out (bias+act), 2 fp32 atomicAdd partial,
//          3 fp32 plain store (row stride OCPAD, block owns its pixels).
template<int NC, int NTAPS, int NT, int ACT, int OUTMODE>
__device__ __forceinline__ void conv_core_lds(
    unsigned short* lds,
    const unsigned short* __restrict__ ah, const unsigned short* __restrict__ al,
    int aC0,
    const unsigned short* __restrict__ wh, const unsigned short* __restrict__ wl,
    const float* __restrict__ bias,
    int b, int mblock, int tap0,
    unsigned short* __restrict__ oh, unsigned short* __restrict__ ol,
    int oC0,
    float* __restrict__ pf)
{
    const int OCPAD = NT * 16;
    unsigned short* Ahl = lds;
    unsigned short* All = lds + AHALF;
    unsigned short* Bhl = lds + 2 * AHALF;
    unsigned short* Bll = lds + 2 * AHALF + OCPAD * APXS;

    int tid = (int)threadIdx.x;
    int wave = tid >> 6;
    int lane = tid & 63;
    int quad = lane >> 4;
    int l16 = lane & 15;

    int pix0 = (mblock * 4 + wave) * 64;   // wave's 64 px = one output row
    int y0 = mblock * 4;                   // block's first (padded) window row

    floatx4 acc[4][NT];
#pragma unroll
    for (int nt = 0; nt < NT; nt++) {
        float bv = (OUTMODE == 1) ? bias[nt * 16 + l16] : 0.f;
#pragma unroll
        for (int mt = 0; mt < 4; mt++) { floatx4 v = {bv, bv, bv, bv}; acc[mt][nt] = v; }
    }

#pragma unroll 1
    for (int ch = 0; ch < NC; ch++) {
        // ---- stage A: 6 rows x 66 px x 32 ushorts (hi+lo) -> padded APXS
        {
            size_t gbase = ((size_t)((aC0 + ch) * 4 + b) * SLAB + (size_t)y0 * 66) * 32;
#pragma unroll
            for (int k = 0; k < 7; k++) {
                int u = k * 256 + tid;          // 16B units, 1584 per half
                if (u < 1584) {
                    int px = u >> 2, j = u & 3;
                    int row = px / 66, col = px - row * 66;
                    int dst = row * AROW + col * APXS + j * 8;
                    *(short8*)(Ahl + dst) = *(const short8*)(ah + gbase + (size_t)u * 8);
                    *(short8*)(All + dst) = *(const short8*)(al + gbase + (size_t)u * 8);
                }
            }
        }
#pragma unroll 1
        for (int tp = 0; tp < NTAPS; tp++) {
            int tap = tap0 + tp;
            int kh = tap / 3, kw = tap - kh * 3;
            // ---- stage B: OCPAD oc x 32 ushorts (hi+lo) -> padded APXS
            {
                size_t wbase = (size_t)(ch * 9 + tap) * OCPAD * 32;
                const int BU = OCPAD * 4;      // 16B units per half
#pragma unroll
                for (int k = 0; k * 256 < BU; k++) {
                    int u = k * 256 + tid;
                    if (u < BU) {
                        int oc = u >> 2, j = u & 3;
                        int dst = oc * APXS + j * 8;
                        *(short8*)(Bhl + dst) = *(const short8*)(wh + wbase + (size_t)u * 8);
                        *(short8*)(Bll + dst) = *(const short8*)(wl + wbase + (size_t)u * 8);
                    }
                }
            }
            __syncthreads();   // staged A(ch) + B(ch,tap) visible

            short8 Afh[4], Afl[4], Bfh[NT], Bfl[NT];
            int arow = (wave + kh) * AROW;
#pragma unroll
            for (int mt = 0; mt < 4; mt++) {
                int aoff = arow + (kw + l16 + mt * 16) * APXS + quad * 8;
                Afh[mt] = *(const short8*)(Ahl + aoff);
                Afl[mt] = *(const short8*)(All + aoff);
            }
#pragma unroll
            for (int nt = 0; nt < NT; nt++) {
                int boff = (nt * 16 + l16) * APXS + quad * 8;
                Bfh[nt] = *(const short8*)(Bhl + boff);
                Bfl[nt] = *(const short8*)(Bll + boff);
            }
#pragma unroll
            for (int nt = 0; nt < NT; nt++) {
#pragma unroll
                for (int mt = 0; mt < 4; mt++) {
                    acc[mt][nt] = __builtin_amdgcn_mfma_f32_16x16x32_bf16(Afh[mt], Bfh[nt], acc[mt][nt], 0, 0, 0);
                    acc[mt][nt] = __builtin_amdgcn_mfma_f32_16x16x32_bf16(Afh[mt], Bfl[nt], acc[mt][nt], 0, 0, 0);
                    acc[mt][nt] = __builtin_amdgcn_mfma_f32_16x16x32_bf16(Afl[mt], Bfh[nt], acc[mt][nt], 0, 0, 0);
                }
            }
            __syncthreads();   // before next stage overwrites A/B
        }
    }

#pragma unroll
    for (int nt = 0; nt < NT; nt++) {
        int oc = nt * 16 + l16;
#pragma unroll
        for (int mt = 0; mt < 4; mt++) {
#pragma unroll
            for (int r = 0; r < 4; r++) {
                float v = acc[mt][nt][r];
                int px = pix0 + mt * 16 + quad * 4 + r;
                if (OUTMODE == 2) {
                    atomicAdd(pf + ((size_t)b * 4096 + px) * OCPAD + oc, v);
                } else if (OUTMODE == 3) {
                    pf[((size_t)b * 4096 + px) * OCPAD + oc] = v;
                } else {
                    if (ACT == 1) v = gelu_exact(v);
                    else if (ACT == 2) v = 1.0f / (1.0f + expf(-v));
                    int yy = (px >> 6) + 1, xx = (px & 63) + 1;
                    int och = oC0 + (oc >> 5);
                    size_t o = ((size_t)(och * 4 + b) * SLAB + yy * 66 + xx) * 32 + (oc & 31);
                    unsigned short hv, lv; split2(v, &hv, &lv);
                    oh[o] = hv; ol[o] = lv;
                }
            }
        }
    }
}

// convA: conv1 (grouped C->C, gelu, direct ->h1pad) + conv3 (256->64, K-split x3 taps -> P3 atomics)
// grid.x = 448 flat. XCD swizzle: xcd = bx&7, j = bx>>3 in [0,56).
//   pair = xcd*8 + j/7  in [0,64)  -> mb = pair&15, b = pair>>4
//   role = j%7: role<4 -> conv1 g=role; else conv3 ks=role-4.
__global__ __launch_bounds__(256, 1) void convA_kernel(
    const unsigned short* __restrict__ xph, const unsigned short* __restrict__ xpl,
    const unsigned short* __restrict__ w1h, const unsigned short* __restrict__ w1l,
    const float* __restrict__ off_b1,
    const unsigned short* __restrict__ w3h, const unsigned short* __restrict__ w3l,
    unsigned short* __restrict__ h1h, unsigned short* __restrict__ h1l,
    float* __restrict__ P3)
{
    __shared__ unsigned short lds[2 * AHALF + 2 * 64 * APXS];   // 73,600 B
    int bx = blockIdx.x;
    int xcd = bx & 7;
    int j = bx >> 3;              // [0,56)
    int pair = xcd * 8 + j / 7;   // [0,64)
    int role = j % 7;
    int mb = pair & 15;
    int b = pair >> 4;
    if (role < 4) {
        int g = role;
        conv_core_lds<2, 9, 4, 1, 1>(lds, xph, xpl, g * 2,
            w1h + (size_t)g * 2 * 9 * 64 * 32, w1l + (size_t)g * 2 * 9 * 64 * 32,
            off_b1 + g * 64,
            b, mb, 0, h1h, h1l, g * 2, nullptr);
    } else {
        int ks = role - 4;         // 0..2 tap groups
        conv_core_lds<8, 3, 4, 0, 2>(lds, xph, xpl, 0, w3h, w3l, nullptr,
            b, mb, ks * 3, nullptr, nullptr, 0, P3);
    }
}

// finalizeA: m1 = gelu(P3 + mod_b1) -> split-bf16.
__global__ __launch_bounds__(256) void finalizeA_kernel(
    const float* __restrict__ P3, const float* __restrict__ mod_b1,
    unsigned short* __restrict__ m1h, unsigned short* __restrict__ m1l)
{
    int idx = blockIdx.x * 256 + threadIdx.x;   // (b*4096+px)*64 + c
    int c = idx & 63;
    int p = idx >> 6;            // b*4096+px
    int b = p >> 12;
    int px = p & 4095;
    int rem = ((px >> 6) + 1) * 66 + (px & 63) + 1;
    float u = P3[(size_t)p * 64 + c] + mod_b1[c];
    u = gelu_exact(u);
    size_t o = ((size_t)((c >> 5) * 4 + b) * SLAB + rem) * 32 + (c & 31);
    unsigned short hu, lu; split2(u, &hu, &lu);
    m1h[o] = hu; m1l[o] = lu;
}

// convB: conv2 (256->80pad, K-split x3 taps -> P2a atomics) + conv4 (64->48pad, un-split, plain stores)
// grid.x = 256 flat. bx<192: conv2: xcd=bx&7, j=bx>>3 in [0,24);
//   pair = xcd*8 + j/3; ks = j%3. bx>=192: conv4: t=bx-192, xcd=t&7, q=t>>3.
__global__ __launch_bounds__(256, 1) void convB_kernel(
    const unsigned short* __restrict__ h1h, const unsigned short* __restrict__ h1l,
    const unsigned short* __restrict__ w2h, const unsigned short* __restrict__ w2l,
    const unsigned short* __restrict__ m1h, const unsigned short* __restrict__ m1l,
    const unsigned short* __restrict__ w4h, const unsigned short* __restrict__ w4l,
    float* __restrict__ P2a, float* __restrict__ P4a)
{
    __shared__ unsigned short lds[2 * AHALF + 2 * 80 * APXS];   // 76,160 B
    int bx = blockIdx.x;
    if (bx < 192) {
        int xcd = bx & 7;
        int j = bx >> 3;              // [0,24)
        int pair = xcd * 8 + j / 3;   // [0,64)
        int ks = j % 3;               // 0..2 tap groups
        int mb = pair & 15;
        int b = pair >> 4;
        conv_core_lds<8, 3, 5, 0, 2>(lds, h1h, h1l, 0, w2h, w2l, nullptr,
            b, mb, ks * 3, nullptr, nullptr, 0, P2a);
    } else {
        int t = bx - 192;
        int xcd = t & 7;
        int q = t >> 3;               // [0,8)
        int pair = xcd * 8 + q;       // [0,64)
        int mb = pair & 15;
        int b = pair >> 4;
        conv_core_lds<2, 9, 3, 0, 3>(lds, m1h, m1l, 0, w4h, w4l, nullptr,
            b, mb, 0, nullptr, nullptr, 0, P4a);
    }
}

// ---------------- merged prep kernel (one dispatch) ----------------
// [0,ZBLK): zero P3+P2a accumulators; [+RBLK): halo ring zero;
// [+XBLK): x -> split-bf16 chunked; [+WBLK): weights -> split-bf16.
#define ZBLK 2304   // (4*4096*(64+80)) floats = 589,824 uint4 / 256
#define RBLK 1040   // 4*260 ring px
#define XBLK 17424  // 4*4356
#define WBLK 1980   // 506,880 weight elements / 256
__global__ void prep_all_kernel(
    const float* __restrict__ x,
    const float* __restrict__ w1f, const float* __restrict__ w2f,
    const float* __restrict__ w3f, const float* __restrict__ w4f,
    unsigned short* __restrict__ xph, unsigned short* __restrict__ xpl,
    unsigned short* __restrict__ h1h, unsigned short* __restrict__ h1l,
    unsigned short* __restrict__ m1h, unsigned short* __restrict__ m1l,
    unsigned short* __restrict__ w1h, unsigned short* __restrict__ w1l,
    unsigned short* __restrict__ w2h, unsigned short* __restrict__ w2l,
    unsigned short* __restrict__ w3h, unsigned short* __restrict__ w3l,
    unsigned short* __restrict__ w4h, unsigned short* __restrict__ w4l,
    float* __restrict__ accf)
{
    int blk = blockIdx.x;
    int t = threadIdx.x;
    if (blk < ZBLK) {
        ((uint4*)accf)[(size_t)blk * 256 + t] = make_uint4(0u, 0u, 0u, 0u);
        return;
    }
    blk -= ZBLK;
    if (blk < RBLK) {
        int b = blk / 260;
        int r = blk - b * 260;
        int i, j;
        if (r < 66)       { i = 0;        j = r; }
        else if (r < 132) { i = 65;       j = r - 66; }
        else if (r < 196) { i = r - 131;  j = 0; }     // rows 1..64
        else              { i = r - 195;  j = 65; }
        size_t pp = (size_t)i * 66 + j;
        int ch = t >> 5, sub = t & 31;
        size_t o = ((size_t)(ch * 4 + b) * SLAB + pp) * 32 + sub;
        h1h[o] = 0; h1l[o] = 0;
        if (t < 64) { m1h[o] = 0; m1l[o] = 0; }
        return;
    }
    blk -= RBLK;
    if (blk < XBLK) {
        int b = blk / 4356;
        int rem = blk - b * 4356;
        int i = rem / 66, j = rem - i * 66;
        float v = 0.f;
        if (i >= 1 && i <= 64 && j >= 1 && j <= 64)
            v = x[((size_t)b * 4096 + (size_t)(i - 1) * 64 + (j - 1)) * 256 + t];
        size_t o = ((size_t)((t >> 5) * 4 + b) * SLAB + rem) * 32 + (t & 31);
        unsigned short h, l; split2(v, &h, &l);
        xph[o] = h; xpl[o] = l;
        return;
    }
    blk -= XBLK;
    {
        const int N1 = 147456, N2 = 184320, N3 = 147456, N4 = 27648;
        int idx = blk * 256 + t;
        const float* w; unsigned short *outh, *outl;
        int ocpad, oc_real, ic, base;
        if (idx < N1)                { w = w1f; outh = w1h; outl = w1l; ocpad = 64; oc_real = 64; ic = 64;  base = 0; }
        else if (idx < N1 + N2)      { w = w2f; outh = w2h; outl = w2l; ocpad = 80; oc_real = 72; ic = 256; base = N1; }
        else if (idx < N1 + N2 + N3) { w = w3f; outh = w3h; outl = w3l; ocpad = 64; oc_real = 64; ic = 256; base = N1 + N2; }
        else                         { w = w4f; outh = w4h; outl = w4l; ocpad = 48; oc_real = 36; ic = 64;  base = N1 + N2 + N3; }
        int lidx = idx - base;
        // lidx -> [g][ch][tap][ocp][ici]
        int ici = lidx & 31;
        int t1 = lidx >> 5;
        int ocp = t1 % ocpad;
        int t2 = t1 / ocpad;
        int tap = t2 % 9;
        int t3 = t2 / 9;
        int nch = ic >> 5;
        int ch = t3 % nch;
        int g = t3 / nch;
        float v = 0.f;
        if (ocp < oc_real) {
            int oc = g * oc_real + ocp;
            int icx = ch * 32 + ici;
            v = w[((size_t)oc * ic + icx) * 9 + tap];
        }
        unsigned short h, l; split2(v, &h, &l);
        outh[lidx] = h; outl[lidx] = l;
    }
}

// ---------------- deformable sampling (exact fp32, finalizeB fused) ----------------
// 4 points per wave, 16 lanes per point, float4 gathers (4 channels/lane).
// XCD swizzle: each XCD gets 512 contiguous blocks (L2-resident x window).
__global__ __launch_bounds__(256) void deform_sample(
    const float* __restrict__ x,
    const float* __restrict__ P2a, const float* __restrict__ P4a,
    const float* __restrict__ b2, const float* __restrict__ b4,
    float* __restrict__ out)
{
    int bid = (int)((blockIdx.x & 7u) * 512u + (blockIdx.x >> 3));   // XCD slab swizzle
    int wid = (int)(((unsigned)bid * 256u + threadIdx.x) >> 6);      // 0..16383
    int lane = (int)(threadIdx.x & 63u);
    int sub = lane >> 4;         // 0..3: which point
    int li = lane & 15;

    int b = wid >> 12;           // 4096 waves per batch
    int rem = wid & 4095;
    int g = rem >> 10;
    int hw = ((rem & 1023) << 2) + sub;
    int hy = hw >> 6;
    int wx = hw & 63;

    // lanes li<9 of each subwave: offsets (P2a+b2) and modulation sigmoid(P4a+b4)
    float fx = 0.f, fy = 0.f, fm = 0.f;
    if (li < 9) {
        size_t p = (size_t)(b << 12) + hw;
        int c2 = g * 18 + li;
        fx = P2a[p * 80 + c2] + b2[c2];
        fy = P2a[p * 80 + 9 + c2] + b2[9 + c2];
        int c4 = g * 9 + li;
        float mv = P4a[p * 48 + c4] + b4[c4];
        fm = 1.0f / (1.0f + expf(-mv));
    }
    float px = fminf(fmaxf((float)wx + (float)(li % 3 - 1) + fx, 0.f), 63.f);
    float py = fminf(fmaxf((float)hy + (float)(li / 3 - 1) + fy, 0.f), 63.f);
    float x0f = floorf(px), y0f = floorf(py);
    float wxf = px - x0f, wyf = py - y0f;
    int x0 = (int)x0f, y0 = (int)y0f;
    int x1 = min(x0 + 1, 63), y1 = min(y0 + 1, 63);

    // lane li gathers channels g*64 + li*4 .. +3 as float4
    const float4* xb = (const float4*)(x + ((size_t)(b << 12)) * 256 + g * 64 + li * 4);
    float4 acc = make_float4(0.f, 0.f, 0.f, 0.f);
    int sb = sub << 4;
#pragma unroll
    for (int q = 0; q < 9; q++) {
        int src = sb + q;
        int   qx0 = __shfl(x0, src);
        int   qx1 = __shfl(x1, src);
        int   qy0 = __shfl(y0, src);
        int   qy1 = __shfl(y1, src);
        float qwx = __shfl(wxf, src);
        float qwy = __shfl(wyf, src);
        float qm  = __shfl(fm, src);
        float4 v00 = xb[(size_t)(qy0 * 64 + qx0) * 64];
        float4 v01 = xb[(size_t)(qy0 * 64 + qx1) * 64];
        float4 v10 = xb[(size_t)(qy1 * 64 + qx0) * 64];
        float4 v11 = xb[(size_t)(qy1 * 64 + qx1) * 64];
        float w00 = (1.f - qwx) * (1.f - qwy);
        float w01 = qwx * (1.f - qwy);
        float w10 = (1.f - qwx) * qwy;
        float w11 = qwx * qwy;
        acc.x += qm * (v00.x * w00 + v01.x * w01 + v10.x * w10 + v11.x * w11);
        acc.y += qm * (v00.y * w00 + v01.y * w01 + v10.y * w10 + v11.y * w11);
        acc.z += qm * (v00.z * w00 + v01.z * w01 + v10.z * w10 + v11.z * w11);
        acc.w += qm * (v00.w * w00 + v01.w * w01 + v10.w * w10 + v11.w * w11);
    }
    const float s = 1.f / 9.f;
    acc.x *= s; acc.y *= s; acc.z *= s; acc.w *= s;
    float4* ob = (float4*)(out + ((size_t)(b << 12) + hw) * 256 + g * 64 + li * 4);
    *ob = acc;
}

extern "C" void kernel_launch(void* const* d_in, const int* in_sizes, int n_in,
                              void* d_out, int out_size, void* d_ws, size_t ws_size,
                              hipStream_t stream)
{
    const float* x      = (const float*)d_in[0];
    const float* off_w1 = (const float*)d_in[1];
    const float* off_b1 = (const float*)d_in[2];
    const float* off_w2 = (const float*)d_in[3];
    const float* off_b2 = (const float*)d_in[4];
    const float* mod_w1 = (const float*)d_in[5];
    const float* mod_b1 = (const float*)d_in[6];
    const float* mod_w2 = (const float*)d_in[7];
    const float* mod_b2 = (const float*)d_in[8];

    // ws layout (ushort units; split hi/lo arrays, 64B px units, SLAB-padded)
    const size_t XP = 8u * 4u * SLAB * 32u;      // 8 chunks x 4 b x SLAB x 32
    const size_t MP = 2u * 4u * SLAB * 32u;      // 2 chunks
    const size_t W1 = 4u * 2u * 9u * 64u * 32u;  // 147,456
    const size_t W2 = 8u * 9u * 80u * 32u;       // 184,320
    const size_t W3 = 8u * 9u * 64u * 32u;       // 147,456
    const size_t W4 = 2u * 9u * 48u * 32u;       // 27,648

    unsigned short* ws = (unsigned short*)d_ws;
    size_t o = 0;
    unsigned short* xph = ws + o; o += XP + AGAP;
    unsigned short* xpl = ws + o; o += XP + AGAP;
    unsigned short* h1h = ws + o; o += XP + AGAP;
    unsigned short* h1l = ws + o; o += XP + AGAP;
    unsigned short* m1h = ws + o; o += MP + AGAP;
    unsigned short* m1l = ws + o; o += MP + AGAP;
    unsigned short* w1h = ws + o; o += W1 + AGAP;
    unsigned short* w1l = ws + o; o += W1 + AGAP;
    unsigned short* w2h = ws + o; o += W2 + AGAP;
    unsigned short* w2l = ws + o; o += W2 + AGAP;
    unsigned short* w3h = ws + o; o += W3 + AGAP;
    unsigned short* w3l = ws + o; o += W3 + AGAP;
    unsigned short* w4h = ws + o; o += W4 + AGAP;
    unsigned short* w4l = ws + o; o += W4 + AGAP;
    o += o & 1;  // align to 4B for float section
    // fp32 accumulators: P3+P2a zeroed by prep seg 0; P4a plain-written (no init)
    float* fbase = (float*)(ws + o);
    float* P3  = fbase;                              // [4*4096][64]
    float* P2a = P3 + (size_t)4 * 4096 * 64;         // [4*4096][80]
    float* P4a = P2a + (size_t)4 * 4096 * 80;        // [4*4096][48]
    const size_t ACC_FLOATS = (size_t)4 * 4096 * (64 + 80 + 48);
    size_t need_bytes = o * 2 + ACC_FLOATS * 4;      // ~56 MB (ws ~268 MB)
    if (ws_size < need_bytes) return;  // deterministic guard

    prep_all_kernel<<<ZBLK + RBLK + XBLK + WBLK, 256, 0, stream>>>(
        x, off_w1, off_w2, mod_w1, mod_w2,
        xph, xpl, h1h, h1l, m1h, m1l,
        w1h, w1l, w2h, w2l, w3h, w3l, w4h, w4l, P3);

    convA_kernel<<<dim3(448, 1, 1), 256, 0, stream>>>(xph, xpl, w1h, w1l, off_b1,
                                                      w3h, w3l, h1h, h1l, P3);
    finalizeA_kernel<<<4096, 256, 0, stream>>>(P3, mod_b1, m1h, m1l);
    convB_kernel<<<dim3(256, 1, 1), 256, 0, stream>>>(h1h, h1l, w2h, w2l,
                                                      m1h, m1l, w4h, w4l, P2a, P4a);
    deform_sample<<<4096, 256, 0, stream>>>(x, P2a, P4a, off_b2, mod_b2, (float*)d_out);
}